// Round 1
// baseline (1316.117 us; speedup 1.0000x reference)
//
#include <hip/hip_runtime.h>

#define N_ENT 500000
#define E_NUM 400000

typedef __attribute__((ext_vector_type(8))) short short8;
typedef __attribute__((ext_vector_type(4))) float f32x4;

static __device__ __forceinline__ unsigned short f2bf(float f) {
    unsigned u = __float_as_uint(f);
    u += 0x7fffu + ((u >> 16) & 1u);
    return (unsigned short)(u >> 16);
}

// Pack B[K][N] (fp32) into bf16 MFMA-fragment-major layout for
// v_mfma_f32_16x16x32_bf16: frag (kb,nb); lane l holds
// B[kb*32 + (l>>4)*8 + j][nb*16 + (l&15)], j=0..7 contiguous (16B/lane).
__global__ void pack_b_kernel(const float* __restrict__ src,
                              unsigned short* __restrict__ dst, int K, int N) {
    int p = blockIdx.x * blockDim.x + threadIdx.x;
    if (p >= K * N) return;
    int j = p & 7;
    int l = (p >> 3) & 63;
    int f = p >> 9;
    int nfr = N >> 4;
    int nb = f % nfr;
    int kb = f / nfr;
    int k = kb * 32 + ((l >> 4) << 3) + j;
    int n = nb * 16 + (l & 15);
    dst[p] = f2bf(src[(size_t)k * N + n]);
}

// LDS tile: 128 rows x 256 bf16, XOR-swizzled to kill the 512B-row-stride
// bank conflict on ds_read_b128 (G4 recipe: byte ^= (row&7)<<4).
__device__ __forceinline__ int lds_off(int row, int colb) {
    return ((row << 9) + colb) ^ ((row & 7) << 4);
}

__global__ __launch_bounds__(512, 2) void fused_mlp(
    const int* __restrict__ ei, const float* __restrict__ attr,
    const float* __restrict__ W1, const float* __restrict__ b1,
    const float* __restrict__ b2, const float* __restrict__ b3,
    const unsigned short* __restrict__ w1rp,
    const unsigned short* __restrict__ w2p,
    const unsigned short* __restrict__ w3p,
    float* __restrict__ out)
{
    __shared__ unsigned short lds_h[128 * 256];  // 64 KB, swizzled addressing
    char* ldsb = (char*)lds_h;

    const int tid = threadIdx.x;
    const int l = tid & 63;
    const int w = tid >> 6;
    const int lr = l & 15;   // A-row / B-col / C-col within frag
    const int lg = l >> 4;   // k-group
    const int stripe = w << 4;  // 8 waves x 16 rows = 128 edges/block

    const int bid = blockIdx.x;
    const int d = bid >= 3125 ? 1 : 0;
    const int t = d ? bid - 3125 : bid;
    const int e0 = t << 7;

    const f32x4 zero = {0.f, 0.f, 0.f, 0.f};

    // ---------------- Phase 1: h = relu(W1_ent[idx] + attr @ W1_rel + b1) ----
    f32x4 acc[16];
    #pragma unroll
    for (int i = 0; i < 16; ++i) acc[i] = zero;

    {
        const float* ap = attr + (size_t)(e0 + stripe + lr) * 64 + (lg << 3);
        #pragma unroll
        for (int kb = 0; kb < 2; ++kb) {
            f32x4 x0 = *(const f32x4*)(ap + kb * 32);
            f32x4 x1 = *(const f32x4*)(ap + kb * 32 + 4);
            short8 af;
            af[0] = (short)f2bf(x0[0]); af[1] = (short)f2bf(x0[1]);
            af[2] = (short)f2bf(x0[2]); af[3] = (short)f2bf(x0[3]);
            af[4] = (short)f2bf(x1[0]); af[5] = (short)f2bf(x1[1]);
            af[6] = (short)f2bf(x1[2]); af[7] = (short)f2bf(x1[3]);
            const short8* bp = (const short8*)w1rp + (size_t)(kb * 16) * 64 + l;
            #pragma unroll
            for (int cf = 0; cf < 16; ++cf)
                acc[cf] = __builtin_amdgcn_mfma_f32_16x16x32_bf16(
                    af, bp[(size_t)cf * 64], acc[cf], 0, 0, 0);
        }
    }
    // Epilogue in MFMA C-layout: add fp32 gather row + b1, relu, -> LDS bf16
    {
        #pragma unroll
        for (int reg = 0; reg < 4; ++reg) {
            int row = stripe + (lg << 2) + reg;
            int id = ei[d * E_NUM + e0 + row];
            const float* gp = W1 + (size_t)id * 256 + lr;
            #pragma unroll
            for (int cf = 0; cf < 16; ++cf) {
                int col = (cf << 4) + lr;
                float v = acc[cf][reg] + gp[cf << 4] + b1[col];
                v = fmaxf(v, 0.f);
                *(unsigned short*)(ldsb + lds_off(row, col << 1)) = f2bf(v);
            }
        }
    }
    __syncthreads();

    // ---------------- Phase 2: h2 = relu(h @ W2 + b2) ----
    #pragma unroll
    for (int i = 0; i < 16; ++i) acc[i] = zero;
    #pragma unroll 2
    for (int kb = 0; kb < 8; ++kb) {
        short8 a = *(const short8*)(ldsb +
            lds_off(stripe + lr, ((kb << 5) + (lg << 3)) << 1));
        const short8* bp = (const short8*)w2p + (size_t)(kb * 16) * 64 + l;
        #pragma unroll
        for (int cf = 0; cf < 16; ++cf)
            acc[cf] = __builtin_amdgcn_mfma_f32_16x16x32_bf16(
                a, bp[(size_t)cf * 64], acc[cf], 0, 0, 0);
    }
    __syncthreads();  // all reads of h done before overwrite
    {
        #pragma unroll
        for (int reg = 0; reg < 4; ++reg) {
            int row = stripe + (lg << 2) + reg;
            #pragma unroll
            for (int cf = 0; cf < 16; ++cf) {
                int col = (cf << 4) + lr;
                float v = fmaxf(acc[cf][reg] + b2[col], 0.f);
                *(unsigned short*)(ldsb + lds_off(row, col << 1)) = f2bf(v);
            }
        }
    }
    __syncthreads();

    // ---------------- Phase 3: out = h2 @ W3 + b3 ----
    f32x4 acc3[8];
    #pragma unroll
    for (int i = 0; i < 8; ++i) acc3[i] = zero;
    #pragma unroll 2
    for (int kb = 0; kb < 8; ++kb) {
        short8 a = *(const short8*)(ldsb +
            lds_off(stripe + lr, ((kb << 5) + (lg << 3)) << 1));
        const short8* bp = (const short8*)w3p + (size_t)(kb * 8) * 64 + l;
        #pragma unroll
        for (int cf = 0; cf < 8; ++cf)
            acc3[cf] = __builtin_amdgcn_mfma_f32_16x16x32_bf16(
                a, bp[(size_t)cf * 64], acc3[cf], 0, 0, 0);
    }
    {
        float* op = out + ((size_t)d * E_NUM + e0) * 128;
        #pragma unroll
        for (int reg = 0; reg < 4; ++reg) {
            int row = stripe + (lg << 2) + reg;
            #pragma unroll
            for (int cf = 0; cf < 8; ++cf) {
                int col = (cf << 4) + lr;
                op[(size_t)row * 128 + col] = acc3[cf][reg] + b3[col];
            }
        }
    }
}

extern "C" void kernel_launch(void* const* d_in, const int* in_sizes, int n_in,
                              void* d_out, int out_size, void* d_ws, size_t ws_size,
                              hipStream_t stream) {
    const int* ei     = (const int*)d_in[0];
    const float* attr = (const float*)d_in[1];
    const float* W1   = (const float*)d_in[2];
    const float* b1   = (const float*)d_in[3];
    const float* W2   = (const float*)d_in[4];
    const float* b2   = (const float*)d_in[5];
    const float* W3   = (const float*)d_in[6];
    const float* b3   = (const float*)d_in[7];
    float* out = (float*)d_out;

    unsigned short* w1rp = (unsigned short*)d_ws;   //  64x256 bf16 =  32 KB
    unsigned short* w2p  = w1rp + 64 * 256;         // 256x256 bf16 = 128 KB
    unsigned short* w3p  = w2p + 256 * 256;         // 256x128 bf16 =  64 KB
    const float* W1rel = W1 + (size_t)N_ENT * 256;

    pack_b_kernel<<<(64 * 256) / 256, 256, 0, stream>>>(W1rel, w1rp, 64, 256);
    pack_b_kernel<<<(256 * 256) / 256, 256, 0, stream>>>(W2, w2p, 256, 256);
    pack_b_kernel<<<(256 * 128) / 256, 256, 0, stream>>>(W3, w3p, 256, 128);

    // 2 directions x 3125 tiles of 128 edges (exact, no tail)
    fused_mlp<<<6250, 512, 0, stream>>>(ei, attr, W1, b1, b2, b3,
                                        w1rp, w2p, w3p, out);
}

// Round 2
// 1316.048 us; speedup vs baseline: 1.0001x; 1.0001x over previous
//
#include <hip/hip_runtime.h>

#define N_ENT 500000
#define E_NUM 400000
#define NTILE 6250
#define NBLOCKS 256

typedef __attribute__((ext_vector_type(8))) short short8;
typedef __attribute__((ext_vector_type(4))) float f32x4;

static __device__ __forceinline__ unsigned short f2bf(float f) {
    unsigned u = __float_as_uint(f);
    u += 0x7fffu + ((u >> 16) & 1u);
    return (unsigned short)(u >> 16);
}

// Pack B[K][N] (fp32) into bf16 MFMA-fragment-major layout for
// v_mfma_f32_16x16x32_bf16: frag f = kb*(N/16)+nb; lane l holds
// B[kb*32 + (l>>4)*8 + j][nb*16 + (l&15)], j=0..7 contiguous (16B/lane).
__global__ void pack_b_kernel(const float* __restrict__ src,
                              unsigned short* __restrict__ dst, int K, int N) {
    int p = blockIdx.x * blockDim.x + threadIdx.x;
    if (p >= K * N) return;
    int j = p & 7;
    int l = (p >> 3) & 63;
    int f = p >> 9;
    int nfr = N >> 4;
    int nb = f % nfr;
    int kb = f / nfr;
    int k = kb * 32 + ((l >> 4) << 3) + j;
    int n = nb * 16 + (l & 15);
    dst[p] = f2bf(src[(size_t)k * N + n]);
}

// LDS tile: 128 rows x 256 bf16, XOR-swizzled (byte ^= (row&7)<<4) so
// ds_read_b128 at row-stride 512B is bank-conflict-free.
__device__ __forceinline__ int lds_off(int row, int colb) {
    return ((row << 9) + colb) ^ ((row & 7) << 4);
}

// Persistent-block fused MLP. 8 waves = 2(M) x 4(N); each wave owns a
// 64x64 slab, holds its W2 slice (32 frags = 128 VGPRs) across all tiles.
__global__ __launch_bounds__(512, 2) void fused_mlp(
    const int* __restrict__ ei, const float* __restrict__ attr,
    const float* __restrict__ W1, const float* __restrict__ b1,
    const float* __restrict__ b2, const float* __restrict__ b3,
    const unsigned short* __restrict__ w1rp,
    const unsigned short* __restrict__ w2p,
    const unsigned short* __restrict__ w3p,
    float* __restrict__ out)
{
    __shared__ unsigned short lds_h[128 * 256];  // 64 KB, swizzled addressing
    char* ldsb = (char*)lds_h;

    const int tid = threadIdx.x;
    const int l = tid & 63;
    const int w = tid >> 6;
    const int lr = l & 15;   // col-in-frag (C) / row-in-frag (A,B)
    const int lg = l >> 4;   // k-group / C row-group
    const int wm = w >> 2;   // M wave group: rows [wm*64, wm*64+64)
    const int wn = w & 3;    // N wave group: cols [wn*64, wn*64+64)
    const int rbase = wm << 6;
    const int cbase = wn << 6;

    const f32x4 zero = {0.f, 0.f, 0.f, 0.f};

    // Preload this wave's W2 slice once per block (128 VGPRs).
    short8 w2reg[8][4];
    #pragma unroll
    for (int kb = 0; kb < 8; ++kb)
        #pragma unroll
        for (int nf = 0; nf < 4; ++nf)
            w2reg[kb][nf] =
                ((const short8*)w2p)[(size_t)(kb * 16 + (wn << 2) + nf) * 64 + l];

    for (int t = blockIdx.x; t < NTILE; t += gridDim.x) {
        const int d = t >= 3125 ? 1 : 0;
        const int e0 = (d ? t - 3125 : t) << 7;

        // ---------- Phase 1 MFMA: attr @ W1_rel (no LDS touched) ----------
        f32x4 acc[4][4];
        #pragma unroll
        for (int i = 0; i < 4; ++i)
            #pragma unroll
            for (int j = 0; j < 4; ++j) acc[i][j] = zero;

        #pragma unroll
        for (int kb = 0; kb < 2; ++kb) {
            short8 b[4];
            #pragma unroll
            for (int nf = 0; nf < 4; ++nf)
                b[nf] = ((const short8*)w1rp)[(size_t)(kb * 16 + (wn << 2) + nf) * 64 + l];
            #pragma unroll
            for (int mr = 0; mr < 4; ++mr) {
                const float* ap = attr +
                    (size_t)(e0 + rbase + mr * 16 + lr) * 64 + (kb << 5) + (lg << 3);
                f32x4 x0 = *(const f32x4*)ap;
                f32x4 x1 = *(const f32x4*)(ap + 4);
                short8 af;
                af[0] = (short)f2bf(x0[0]); af[1] = (short)f2bf(x0[1]);
                af[2] = (short)f2bf(x0[2]); af[3] = (short)f2bf(x0[3]);
                af[4] = (short)f2bf(x1[0]); af[5] = (short)f2bf(x1[1]);
                af[6] = (short)f2bf(x1[2]); af[7] = (short)f2bf(x1[3]);
                #pragma unroll
                for (int nf = 0; nf < 4; ++nf)
                    acc[mr][nf] = __builtin_amdgcn_mfma_f32_16x16x32_bf16(
                        af, b[nf], acc[mr][nf], 0, 0, 0);
            }
        }

        __syncthreads();  // previous tile's phase-3 LDS reads are done

        // ---------- Phase 1 epilogue: + gather + b1, relu -> LDS ----------
        #pragma unroll
        for (int mr = 0; mr < 4; ++mr) {
            #pragma unroll
            for (int reg = 0; reg < 4; ++reg) {
                int row = rbase + mr * 16 + (lg << 2) + reg;
                int id = ei[d * E_NUM + e0 + row];
                const float* gp = W1 + (size_t)id * 256 + cbase + lr;
                #pragma unroll
                for (int nf = 0; nf < 4; ++nf) {
                    int col = cbase + (nf << 4) + lr;
                    float v = acc[mr][nf][reg] + gp[nf << 4] + b1[col];
                    v = fmaxf(v, 0.f);
                    *(unsigned short*)(ldsb + lds_off(row, col << 1)) = f2bf(v);
                }
            }
        }
        __syncthreads();

        // ---------- Phase 2: h2 = relu(h @ W2 + b2), W2 from VGPRs ----------
        #pragma unroll
        for (int i = 0; i < 4; ++i)
            #pragma unroll
            for (int j = 0; j < 4; ++j) acc[i][j] = zero;

        #pragma unroll
        for (int kb = 0; kb < 8; ++kb) {
            short8 a[4];
            #pragma unroll
            for (int mr = 0; mr < 4; ++mr)
                a[mr] = *(const short8*)(ldsb +
                    lds_off(rbase + mr * 16 + lr, ((kb << 5) + (lg << 3)) << 1));
            #pragma unroll
            for (int mr = 0; mr < 4; ++mr)
                #pragma unroll
                for (int nf = 0; nf < 4; ++nf)
                    acc[mr][nf] = __builtin_amdgcn_mfma_f32_16x16x32_bf16(
                        a[mr], w2reg[kb][nf], acc[mr][nf], 0, 0, 0);
        }
        __syncthreads();  // all phase-2 reads of h done before overwrite

        #pragma unroll
        for (int mr = 0; mr < 4; ++mr) {
            #pragma unroll
            for (int reg = 0; reg < 4; ++reg) {
                int row = rbase + mr * 16 + (lg << 2) + reg;
                #pragma unroll
                for (int nf = 0; nf < 4; ++nf) {
                    int col = cbase + (nf << 4) + lr;
                    float v = fmaxf(acc[mr][nf][reg] + b2[col], 0.f);
                    *(unsigned short*)(ldsb + lds_off(row, col << 1)) = f2bf(v);
                }
            }
        }
        __syncthreads();

        // ---------- Phase 3: out = h2 @ W3 + b3 ----------
        f32x4 acc3[4][2];
        #pragma unroll
        for (int i = 0; i < 4; ++i) {
            acc3[i][0] = zero; acc3[i][1] = zero;
        }
        #pragma unroll
        for (int kb = 0; kb < 8; ++kb) {
            short8 b[2];
            #pragma unroll
            for (int nf = 0; nf < 2; ++nf)
                b[nf] = ((const short8*)w3p)[(size_t)(kb * 8 + (wn << 1) + nf) * 64 + l];
            short8 a[4];
            #pragma unroll
            for (int mr = 0; mr < 4; ++mr)
                a[mr] = *(const short8*)(ldsb +
                    lds_off(rbase + mr * 16 + lr, ((kb << 5) + (lg << 3)) << 1));
            #pragma unroll
            for (int mr = 0; mr < 4; ++mr)
                #pragma unroll
                for (int nf = 0; nf < 2; ++nf)
                    acc3[mr][nf] = __builtin_amdgcn_mfma_f32_16x16x32_bf16(
                        a[mr], b[nf], acc3[mr][nf], 0, 0, 0);
        }

        {
            float* op = out + ((size_t)d * E_NUM + e0) * 128;
            #pragma unroll
            for (int mr = 0; mr < 4; ++mr) {
                #pragma unroll
                for (int reg = 0; reg < 4; ++reg) {
                    int row = rbase + mr * 16 + (lg << 2) + reg;
                    #pragma unroll
                    for (int nf = 0; nf < 2; ++nf) {
                        int col = (wn << 5) + (nf << 4) + lr;
                        op[(size_t)row * 128 + col] = acc3[mr][nf][reg] + b3[col];
                    }
                }
            }
        }
    }
}

extern "C" void kernel_launch(void* const* d_in, const int* in_sizes, int n_in,
                              void* d_out, int out_size, void* d_ws, size_t ws_size,
                              hipStream_t stream) {
    const int* ei     = (const int*)d_in[0];
    const float* attr = (const float*)d_in[1];
    const float* W1   = (const float*)d_in[2];
    const float* b1   = (const float*)d_in[3];
    const float* W2   = (const float*)d_in[4];
    const float* b2   = (const float*)d_in[5];
    const float* W3   = (const float*)d_in[6];
    const float* b3   = (const float*)d_in[7];
    float* out = (float*)d_out;

    unsigned short* w1rp = (unsigned short*)d_ws;   //  64x256 bf16 =  32 KB
    unsigned short* w2p  = w1rp + 64 * 256;         // 256x256 bf16 = 128 KB
    unsigned short* w3p  = w2p + 256 * 256;         // 256x128 bf16 =  64 KB
    const float* W1rel = W1 + (size_t)N_ENT * 256;

    pack_b_kernel<<<(64 * 256) / 256, 256, 0, stream>>>(W1rel, w1rp, 64, 256);
    pack_b_kernel<<<(256 * 256) / 256, 256, 0, stream>>>(W2, w2p, 256, 256);
    pack_b_kernel<<<(256 * 128) / 256, 256, 0, stream>>>(W3, w3p, 256, 128);

    fused_mlp<<<NBLOCKS, 512, 0, stream>>>(ei, attr, W1, b1, b2, b3,
                                           w1rp, w2p, w3p, out);
}

// Round 4
// 547.370 us; speedup vs baseline: 2.4044x; 2.4043x over previous
//
#include <hip/hip_runtime.h>

#define N_ENT 500000
#define E_NUM 400000

typedef __attribute__((ext_vector_type(8))) short short8;
typedef __attribute__((ext_vector_type(4))) float f32x4;

static __device__ __forceinline__ unsigned short f2bf(float f) {
    unsigned u = __float_as_uint(f);
    u += 0x7fffu + ((u >> 16) & 1u);
    return (unsigned short)(u >> 16);
}
static __device__ __forceinline__ float bf2f(unsigned short s) {
    return __uint_as_float(((unsigned)s) << 16);
}

// Pack B[K][N] (fp32) into bf16 MFMA-fragment-major layout for
// v_mfma_f32_16x16x32_bf16: frag f = kb*(N/16)+nb; lane l holds
// B[kb*32 + (l>>4)*8 + j][nb*16 + (l&15)], j=0..7 contiguous (16B/lane).
__global__ void pack_b_kernel(const float* __restrict__ src,
                              unsigned short* __restrict__ dst, int K, int N) {
    int p = blockIdx.x * blockDim.x + threadIdx.x;
    if (p >= K * N) return;
    int j = p & 7;
    int l = (p >> 3) & 63;
    int f = p >> 9;
    int nfr = N >> 4;
    int nb = f % nfr;
    int kb = f / nfr;
    int k = kb * 32 + ((l >> 4) << 3) + j;
    int n = nb * 16 + (l & 15);
    dst[p] = f2bf(src[(size_t)k * N + n]);
}

// Swizzled h-tile addressing (rows x 256 bf16, row stride 512B):
// byte ^= (row&7)<<4 kills the 512B-stride bank conflict on ds_read_b128.
__device__ __forceinline__ int lds_off(int row, int colb) {
    return ((row << 9) + colb) ^ ((row & 7) << 4);
}

// ================= Kernel A: X = relu(gather + attr@W1rel + b1) ============
// 64 edges/block, 256 thr (4 waves, 1 row-frag each). Burst gather: each
// entity row fetched as 4 back-to-back dwordx4 instrs over 16 contiguous
// lanes = one 1KB DRAM-row burst, issued BEFORE the MFMA (latency hidden).
// X stored PRE-SWIZZLED (physical h-LDS image) so mlp23 can DMA it linearly.
__global__ __launch_bounds__(256, 2) void mlp1_gather(
    const int* __restrict__ ei, const float* __restrict__ attr,
    const float* __restrict__ W1, const float* __restrict__ b1,
    const unsigned short* __restrict__ w1rp, unsigned short* __restrict__ X)
{
    // G: 64 rows x 264 shorts (stride 528B, pad vs bank conflicts) = 33792 B
    // h: 64 rows x 256 bf16 swizzled                               = 32768 B
    __shared__ char smem[64 * 528 + 64 * 512];
    short* G = (short*)smem;
    char* hb = smem + 64 * 528;

    const int tid = threadIdx.x;
    const int l = tid & 63;
    const int wv = tid >> 6;
    const int lr = l & 15;
    const int lg = l >> 4;
    const int r0 = wv << 4;

    const int bid = blockIdx.x;
    const int d = bid >= 6250 ? 1 : 0;
    const int e0 = (d ? bid - 6250 : bid) << 6;

    // --- ids for this wave's 16 rows (4 per sub-pass, lane l>>4 picks row)
    int ids[4];
    #pragma unroll
    for (int q = 0; q < 4; ++q)
        ids[q] = ei[d * E_NUM + e0 + r0 + (q << 2) + (l >> 4)];

    // --- issue attr loads (MFMA needs these first)
    const float* ap = attr + (size_t)(e0 + r0 + lr) * 64 + (lg << 3);
    f32x4 ax[2][2];
    #pragma unroll
    for (int kb = 0; kb < 2; ++kb) {
        ax[kb][0] = *(const f32x4*)(ap + (kb << 5));
        ax[kb][1] = *(const f32x4*)(ap + (kb << 5) + 4);
    }

    // --- issue burst gathers: row (q, l>>4), lane chunk (l&15)*16B, 4 pages
    f32x4 g[4][4];
    #pragma unroll
    for (int q = 0; q < 4; ++q) {
        const float* gp = W1 + (size_t)ids[q] * 256 + ((l & 15) << 2);
        #pragma unroll
        for (int k = 0; k < 4; ++k)
            g[q][k] = *(const f32x4*)(gp + (k << 6));
    }

    // --- b1 slice for this thread
    float bv1[16];
    #pragma unroll
    for (int cf = 0; cf < 16; ++cf) bv1[cf] = b1[(cf << 4) + lr];

    // --- rel_proj MFMA (waits only on attr; gathers stay in flight)
    const f32x4 zero = {0.f, 0.f, 0.f, 0.f};
    f32x4 acc[16];
    #pragma unroll
    for (int i = 0; i < 16; ++i) acc[i] = zero;
    #pragma unroll
    for (int kb = 0; kb < 2; ++kb) {
        short8 af;
        #pragma unroll
        for (int j = 0; j < 4; ++j) {
            af[j] = (short)f2bf(ax[kb][0][j]);
            af[j + 4] = (short)f2bf(ax[kb][1][j]);
        }
        #pragma unroll
        for (int cf = 0; cf < 16; ++cf)
            acc[cf] = __builtin_amdgcn_mfma_f32_16x16x32_bf16(
                af, ((const short8*)w1rp)[(size_t)(kb * 16 + cf) * 64 + l],
                acc[cf], 0, 0, 0);
    }

    // --- land gathers into G as bf16 (row-major, stride 264 shorts)
    #pragma unroll
    for (int q = 0; q < 4; ++q) {
        int row = r0 + (q << 2) + (l >> 4);
        #pragma unroll
        for (int k = 0; k < 4; ++k) {
            unsigned lo = ((unsigned)f2bf(g[q][k][1]) << 16) | f2bf(g[q][k][0]);
            unsigned hi = ((unsigned)f2bf(g[q][k][3]) << 16) | f2bf(g[q][k][2]);
            unsigned* dst = (unsigned*)(G + row * 264 + (k << 6) + ((l & 15) << 2));
            dst[0] = lo;
            dst[1] = hi;
        }
    }
    __syncthreads();

    // --- epilogue: acc + gather + b1, relu -> swizzled h
    #pragma unroll
    for (int reg = 0; reg < 4; ++reg) {
        int row = r0 + (lg << 2) + reg;
        #pragma unroll
        for (int cf = 0; cf < 16; ++cf) {
            int col = (cf << 4) + lr;
            float v = acc[cf][reg] + bf2f((unsigned short)G[row * 264 + col]) + bv1[cf];
            v = fmaxf(v, 0.f);
            *(unsigned short*)(hb + lds_off(row, col << 1)) = f2bf(v);
        }
    }
    __syncthreads();

    // --- dump physical h image -> X (pure coalesced memcpy, full lines)
    char* dst = (char*)X + ((size_t)(d * E_NUM + e0)) * 512 + tid * 128;
    #pragma unroll
    for (int i = 0; i < 8; ++i)
        *(f32x4*)(dst + (i << 4)) = *(const f32x4*)(hb + tid * 128 + (i << 4));
}

// ================= Kernel B: out = relu(X@W2+b2)@W3 + b3 ==================
// 128 rows/block, 512 thr = 8 waves (2M x 4N). X DMA'd via global_load_lds
// (X is already the swizzled LDS image, so dest stays linear).
__global__ __launch_bounds__(512, 4) void mlp23(
    const unsigned short* __restrict__ X, const float* __restrict__ b2,
    const float* __restrict__ b3, const unsigned short* __restrict__ w2p,
    const unsigned short* __restrict__ w3p, float* __restrict__ out)
{
    __shared__ char smem[128 * 512];  // h / h2, swizzled image
    const int tid = threadIdx.x;
    const int l = tid & 63;
    const int w = tid >> 6;
    const int lr = l & 15;
    const int lg = l >> 4;
    const int wm = w >> 2;
    const int wn = w & 3;
    const int rbase = wm << 6;
    const int cbase = wn << 6;

    const int bid = blockIdx.x;
    const int d = bid >= 3125 ? 1 : 0;
    const int e0 = (d ? bid - 3125 : bid) << 7;

    // --- DMA X tile (64 KB) into LDS, 8 x 1KB per wave
    {
        const char* Xt = (const char*)X + ((size_t)(d * E_NUM + e0)) * 512;
        #pragma unroll
        for (int i = 0; i < 8; ++i)
            __builtin_amdgcn_global_load_lds(
                (const unsigned int*)(Xt + (w << 13) + (i << 10) + (l << 4)),
                (unsigned int*)(smem + (w << 13) + (i << 10)), 16, 0, 0);
    }

    float bv2[4], bv3[2];
    #pragma unroll
    for (int nf = 0; nf < 4; ++nf) bv2[nf] = b2[cbase + (nf << 4) + lr];
    #pragma unroll
    for (int nf = 0; nf < 2; ++nf) bv3[nf] = b3[(wn << 5) + (nf << 4) + lr];

    __syncthreads();  // drains the DMA (barrier implies vmcnt(0))

    const f32x4 zero = {0.f, 0.f, 0.f, 0.f};

    // --- Phase 2: h2 = relu(h @ W2 + b2)
    f32x4 acc[4][4];
    #pragma unroll
    for (int i = 0; i < 4; ++i)
        #pragma unroll
        for (int j = 0; j < 4; ++j) acc[i][j] = zero;

    #pragma unroll 2
    for (int kb = 0; kb < 8; ++kb) {
        short8 a[4];
        #pragma unroll
        for (int mr = 0; mr < 4; ++mr)
            a[mr] = *(const short8*)(smem +
                lds_off(rbase + mr * 16 + lr, ((kb << 5) + (lg << 3)) << 1));
        #pragma unroll
        for (int mr = 0; mr < 4; ++mr)
            #pragma unroll
            for (int nf = 0; nf < 4; ++nf)
                acc[mr][nf] = __builtin_amdgcn_mfma_f32_16x16x32_bf16(
                    a[mr],
                    ((const short8*)w2p)[(size_t)(kb * 16 + (wn << 2) + nf) * 64 + l],
                    acc[mr][nf], 0, 0, 0);
    }
    __syncthreads();  // all reads of h done before overwrite

    #pragma unroll
    for (int mr = 0; mr < 4; ++mr)
        #pragma unroll
        for (int reg = 0; reg < 4; ++reg) {
            int row = rbase + mr * 16 + (lg << 2) + reg;
            #pragma unroll
            for (int nf = 0; nf < 4; ++nf) {
                int col = cbase + (nf << 4) + lr;
                float v = fmaxf(acc[mr][nf][reg] + bv2[nf], 0.f);
                *(unsigned short*)(smem + lds_off(row, col << 1)) = f2bf(v);
            }
        }
    __syncthreads();

    // --- Phase 3: out = h2 @ W3 + b3
    f32x4 acc3[4][2];
    #pragma unroll
    for (int i = 0; i < 4; ++i) { acc3[i][0] = zero; acc3[i][1] = zero; }

    #pragma unroll 2
    for (int kb = 0; kb < 8; ++kb) {
        short8 a[4];
        #pragma unroll
        for (int mr = 0; mr < 4; ++mr)
            a[mr] = *(const short8*)(smem +
                lds_off(rbase + mr * 16 + lr, ((kb << 5) + (lg << 3)) << 1));
        #pragma unroll
        for (int mr = 0; mr < 4; ++mr)
            #pragma unroll
            for (int nf = 0; nf < 2; ++nf)
                acc3[mr][nf] = __builtin_amdgcn_mfma_f32_16x16x32_bf16(
                    a[mr],
                    ((const short8*)w3p)[(size_t)(kb * 8 + (wn << 1) + nf) * 64 + l],
                    acc3[mr][nf], 0, 0, 0);
    }

    float* op = out + ((size_t)d * E_NUM + e0) * 128;
    #pragma unroll
    for (int mr = 0; mr < 4; ++mr)
        #pragma unroll
        for (int reg = 0; reg < 4; ++reg) {
            int row = rbase + mr * 16 + (lg << 2) + reg;
            #pragma unroll
            for (int nf = 0; nf < 2; ++nf) {
                int col = (wn << 5) + (nf << 4) + lr;
                op[(size_t)row * 128 + col] = acc3[mr][nf][reg] + bv3[nf];
            }
        }
}

// ================= Fallback: round-2 fused kernel (if ws too small) ========
__global__ __launch_bounds__(512, 2) void fused_mlp(
    const int* __restrict__ ei, const float* __restrict__ attr,
    const float* __restrict__ W1, const float* __restrict__ b1,
    const float* __restrict__ b2, const float* __restrict__ b3,
    const unsigned short* __restrict__ w1rp,
    const unsigned short* __restrict__ w2p,
    const unsigned short* __restrict__ w3p,
    float* __restrict__ out)
{
    __shared__ unsigned short lds_h[128 * 256];
    char* ldsb = (char*)lds_h;
    const int tid = threadIdx.x;
    const int l = tid & 63;
    const int w = tid >> 6;
    const int lr = l & 15;
    const int lg = l >> 4;
    const int wm = w >> 2;
    const int wn = w & 3;
    const int rbase = wm << 6;
    const int cbase = wn << 6;
    const f32x4 zero = {0.f, 0.f, 0.f, 0.f};

    for (int t = blockIdx.x; t < 6250; t += gridDim.x) {
        const int d = t >= 3125 ? 1 : 0;
        const int e0 = (d ? t - 3125 : t) << 7;
        f32x4 acc[4][4];
        #pragma unroll
        for (int i = 0; i < 4; ++i)
            #pragma unroll
            for (int j = 0; j < 4; ++j) acc[i][j] = zero;
        #pragma unroll
        for (int kb = 0; kb < 2; ++kb) {
            short8 b[4];
            #pragma unroll
            for (int nf = 0; nf < 4; ++nf)
                b[nf] = ((const short8*)w1rp)[(size_t)(kb * 16 + (wn << 2) + nf) * 64 + l];
            #pragma unroll
            for (int mr = 0; mr < 4; ++mr) {
                const float* ap = attr +
                    (size_t)(e0 + rbase + mr * 16 + lr) * 64 + (kb << 5) + (lg << 3);
                f32x4 x0 = *(const f32x4*)ap;
                f32x4 x1 = *(const f32x4*)(ap + 4);
                short8 af;
                #pragma unroll
                for (int j = 0; j < 4; ++j) {
                    af[j] = (short)f2bf(x0[j]);
                    af[j + 4] = (short)f2bf(x1[j]);
                }
                #pragma unroll
                for (int nf = 0; nf < 4; ++nf)
                    acc[mr][nf] = __builtin_amdgcn_mfma_f32_16x16x32_bf16(
                        af, b[nf], acc[mr][nf], 0, 0, 0);
            }
        }
        __syncthreads();
        #pragma unroll
        for (int mr = 0; mr < 4; ++mr)
            #pragma unroll
            for (int reg = 0; reg < 4; ++reg) {
                int row = rbase + mr * 16 + (lg << 2) + reg;
                int id = ei[d * E_NUM + e0 + row];
                const float* gp = W1 + (size_t)id * 256 + cbase + lr;
                #pragma unroll
                for (int nf = 0; nf < 4; ++nf) {
                    int col = cbase + (nf << 4) + lr;
                    float v = acc[mr][nf][reg] + gp[nf << 4] + b1[col];
                    *(unsigned short*)(ldsb + lds_off(row, col << 1)) = f2bf(fmaxf(v, 0.f));
                }
            }
        __syncthreads();
        #pragma unroll
        for (int i = 0; i < 4; ++i)
            #pragma unroll
            for (int j = 0; j < 4; ++j) acc[i][j] = zero;
        #pragma unroll 2
        for (int kb = 0; kb < 8; ++kb) {
            short8 a[4];
            #pragma unroll
            for (int mr = 0; mr < 4; ++mr)
                a[mr] = *(const short8*)(ldsb +
                    lds_off(rbase + mr * 16 + lr, ((kb << 5) + (lg << 3)) << 1));
            #pragma unroll
            for (int mr = 0; mr < 4; ++mr)
                #pragma unroll
                for (int nf = 0; nf < 4; ++nf)
                    acc[mr][nf] = __builtin_amdgcn_mfma_f32_16x16x32_bf16(
                        a[mr],
                        ((const short8*)w2p)[(size_t)(kb * 16 + (wn << 2) + nf) * 64 + l],
                        acc[mr][nf], 0, 0, 0);
        }
        __syncthreads();
        #pragma unroll
        for (int mr = 0; mr < 4; ++mr)
            #pragma unroll
            for (int reg = 0; reg < 4; ++reg) {
                int row = rbase + mr * 16 + (lg << 2) + reg;
                #pragma unroll
                for (int nf = 0; nf < 4; ++nf) {
                    int col = cbase + (nf << 4) + lr;
                    float v = fmaxf(acc[mr][nf][reg] + b2[col], 0.f);
                    *(unsigned short*)(ldsb + lds_off(row, col << 1)) = f2bf(v);
                }
            }
        __syncthreads();
        f32x4 acc3[4][2];
        #pragma unroll
        for (int i = 0; i < 4; ++i) { acc3[i][0] = zero; acc3[i][1] = zero; }
        #pragma unroll 2
        for (int kb = 0; kb < 8; ++kb) {
            short8 a[4];
            #pragma unroll
            for (int mr = 0; mr < 4; ++mr)
                a[mr] = *(const short8*)(ldsb +
                    lds_off(rbase + mr * 16 + lr, ((kb << 5) + (lg << 3)) << 1));
            #pragma unroll
            for (int mr = 0; mr < 4; ++mr)
                #pragma unroll
                for (int nf = 0; nf < 2; ++nf)
                    acc3[mr][nf] = __builtin_amdgcn_mfma_f32_16x16x32_bf16(
                        a[mr],
                        ((const short8*)w3p)[(size_t)(kb * 8 + (wn << 1) + nf) * 64 + l],
                        acc3[mr][nf], 0, 0, 0);
        }
        float* op = out + ((size_t)d * E_NUM + e0) * 128;
        #pragma unroll
        for (int mr = 0; mr < 4; ++mr)
            #pragma unroll
            for (int reg = 0; reg < 4; ++reg) {
                int row = rbase + mr * 16 + (lg << 2) + reg;
                #pragma unroll
                for (int nf = 0; nf < 2; ++nf) {
                    int col = (wn << 5) + (nf << 4) + lr;
                    op[(size_t)row * 128 + col] = acc3[mr][nf][reg] + b3[col];
                }
            }
    }
}

extern "C" void kernel_launch(void* const* d_in, const int* in_sizes, int n_in,
                              void* d_out, int out_size, void* d_ws, size_t ws_size,
                              hipStream_t stream) {
    const int* ei     = (const int*)d_in[0];
    const float* attr = (const float*)d_in[1];
    const float* W1   = (const float*)d_in[2];
    const float* b1   = (const float*)d_in[3];
    const float* W2   = (const float*)d_in[4];
    const float* b2   = (const float*)d_in[5];
    const float* W3   = (const float*)d_in[6];
    const float* b3   = (const float*)d_in[7];
    float* out = (float*)d_out;
    const float* W1rel = W1 + (size_t)N_ENT * 256;

    const size_t Xbytes = (size_t)2 * E_NUM * 256 * 2;  // 409.6 MB
    const size_t packBytes = (size_t)(64 * 256 + 256 * 256 + 256 * 128) * 2;

    if (ws_size >= Xbytes + packBytes) {
        unsigned short* X    = (unsigned short*)d_ws;
        unsigned short* w1rp = (unsigned short*)((char*)d_ws + Xbytes);
        unsigned short* w2p  = w1rp + 64 * 256;
        unsigned short* w3p  = w2p + 256 * 256;
        pack_b_kernel<<<(64 * 256) / 256, 256, 0, stream>>>(W1rel, w1rp, 64, 256);
        pack_b_kernel<<<(256 * 256) / 256, 256, 0, stream>>>(W2, w2p, 256, 256);
        pack_b_kernel<<<(256 * 128) / 256, 256, 0, stream>>>(W3, w3p, 256, 128);
        mlp1_gather<<<12500, 256, 0, stream>>>(ei, attr, W1, b1, w1rp, X);
        mlp23<<<6250, 512, 0, stream>>>(X, b2, b3, w2p, w3p, out);
    } else {
        unsigned short* w1rp = (unsigned short*)d_ws;
        unsigned short* w2p  = w1rp + 64 * 256;
        unsigned short* w3p  = w2p + 256 * 256;
        pack_b_kernel<<<(64 * 256) / 256, 256, 0, stream>>>(W1rel, w1rp, 64, 256);
        pack_b_kernel<<<(256 * 256) / 256, 256, 0, stream>>>(W2, w2p, 256, 256);
        pack_b_kernel<<<(256 * 128) / 256, 256, 0, stream>>>(W3, w3p, 256, 128);
        fused_mlp<<<256, 512, 0, stream>>>(ei, attr, W1, b1, b2, b3,
                                           w1rp, w2p, w3p, out);
    }
}

// Round 5
// 424.030 us; speedup vs baseline: 3.1038x; 1.2909x over previous
//
#include <hip/hip_runtime.h>

#define N_ENT 500000
#define E_NUM 400000

typedef __attribute__((ext_vector_type(8))) short short8;
typedef __attribute__((ext_vector_type(4))) float f32x4;

static __device__ __forceinline__ unsigned short f2bf(float f) {
    unsigned u = __float_as_uint(f);
    u += 0x7fffu + ((u >> 16) & 1u);
    return (unsigned short)(u >> 16);
}
static __device__ __forceinline__ float bf2f(unsigned short s) {
    return __uint_as_float(((unsigned)s) << 16);
}

// Pack B[K][N] (fp32) into bf16 MFMA-fragment-major layout for
// v_mfma_f32_16x16x32_bf16: frag f = kb*(N/16)+nb; lane l holds
// B[kb*32 + (l>>4)*8 + j][nb*16 + (l&15)], j=0..7 contiguous (16B/lane).
__global__ void pack_b_kernel(const float* __restrict__ src,
                              unsigned short* __restrict__ dst, int K, int N) {
    int p = blockIdx.x * blockDim.x + threadIdx.x;
    if (p >= K * N) return;
    int j = p & 7;
    int l = (p >> 3) & 63;
    int f = p >> 9;
    int nfr = N >> 4;
    int nb = f % nfr;
    int kb = f / nfr;
    int k = kb * 32 + ((l >> 4) << 3) + j;
    int n = nb * 16 + (l & 15);
    dst[p] = f2bf(src[(size_t)k * N + n]);
}

// Swizzled tile addressing (rows x 256 bf16, row stride 512B):
// byte ^= (row&7)<<4 kills the 512B-stride bank conflict on ds_read_b128.
// Swizzle only flips byte bits 4..6, so 8B/16B chunks move as units.
__device__ __forceinline__ int lds_off(int row, int colb) {
    return ((row << 9) + colb) ^ ((row & 7) << 4);
}

// ===== Fully fused: out = relu(relu(gather + attr@W1r + b1)@W2 + b2)@W3 + b3
// 64 edges/block, 256 thr = 4 waves. Phase 1: each wave owns 16 rows,
// all 256 cols (burst-gather its rows, land at swizzled LDS positions,
// RMW epilogue). Phases 2/3: wave owns a 64-col slice, in-place h->h2.
__global__ __launch_bounds__(256, 4) void fused2(
    const int* __restrict__ ei, const float* __restrict__ attr,
    const float* __restrict__ W1, const float* __restrict__ b1,
    const float* __restrict__ b2, const float* __restrict__ b3,
    const unsigned short* __restrict__ w1rp,
    const unsigned short* __restrict__ w2p,
    const unsigned short* __restrict__ w3p,
    float* __restrict__ out)
{
    __shared__ char hb[64 * 512];  // 32 KB: G -> h -> h2, swizzled image

    const int tid = threadIdx.x;
    const int l = tid & 63;
    const int wv = tid >> 6;
    const int lr = l & 15;      // frag col (C) / frag row (A,B)
    const int lg = l >> 4;      // k-group / C row-group
    const int r0 = wv << 4;     // this wave's 16 rows (phase 1 / gather)
    const int myrow = l >> 4;   // gather: row-within-quad
    const int mycol = l & 15;   // gather: 16B chunk

    const int bid = blockIdx.x;
    const int d = bid >= 6250 ? 1 : 0;
    const int e0 = (d ? bid - 6250 : bid) << 6;

    // --- ids (broadcast loads: 16 lanes share each address)
    int ids[4];
    #pragma unroll
    for (int q = 0; q < 4; ++q)
        ids[q] = ei[d * E_NUM + e0 + r0 + (q << 2) + myrow];

    // --- issue all 16 burst gathers (1KB/row as 4 back-to-back dwordx4)
    f32x4 g[4][4];
    #pragma unroll
    for (int q = 0; q < 4; ++q) {
        const float* gp = W1 + (size_t)ids[q] * 256 + (mycol << 2);
        #pragma unroll
        for (int k = 0; k < 4; ++k)
            g[q][k] = *(const f32x4*)(gp + (k << 6));
    }

    // --- issue attr loads (overlap with gather flight)
    const float* ap = attr + (size_t)(e0 + r0 + lr) * 64 + (lg << 3);
    f32x4 ax[2][2];
    #pragma unroll
    for (int kb = 0; kb < 2; ++kb) {
        ax[kb][0] = *(const f32x4*)(ap + (kb << 5));
        ax[kb][1] = *(const f32x4*)(ap + (kb << 5) + 4);
    }

    // --- land gathers at SWIZZLED positions (bf16); g regs die here
    #pragma unroll
    for (int q = 0; q < 4; ++q) {
        int row = r0 + (q << 2) + myrow;
        #pragma unroll
        for (int k = 0; k < 4; ++k) {
            unsigned lo = ((unsigned)f2bf(g[q][k][1]) << 16) | f2bf(g[q][k][0]);
            unsigned hi = ((unsigned)f2bf(g[q][k][3]) << 16) | f2bf(g[q][k][2]);
            int a = lds_off(row, (k << 7) + (mycol << 3));
            *(unsigned*)(hb + a) = lo;
            *(unsigned*)(hb + a + 4) = hi;
        }
    }

    // --- phase 1 MFMA: rel_proj = attr @ W1r (acc[cf] covers all 256 cols)
    const f32x4 zero = {0.f, 0.f, 0.f, 0.f};
    f32x4 acc[16];
    #pragma unroll
    for (int i = 0; i < 16; ++i) acc[i] = zero;
    #pragma unroll
    for (int kb = 0; kb < 2; ++kb) {
        short8 af;
        #pragma unroll
        for (int j = 0; j < 4; ++j) {
            af[j] = (short)f2bf(ax[kb][0][j]);
            af[j + 4] = (short)f2bf(ax[kb][1][j]);
        }
        #pragma unroll
        for (int cf = 0; cf < 16; ++cf)
            acc[cf] = __builtin_amdgcn_mfma_f32_16x16x32_bf16(
                af, ((const short8*)w1rp)[(size_t)(kb * 16 + cf) * 64 + l],
                acc[cf], 0, 0, 0);
    }

    // --- epilogue: same-address RMW (wave-local rows; DS in-order per wave)
    #pragma unroll
    for (int reg = 0; reg < 4; ++reg) {
        int row = r0 + (lg << 2) + reg;
        #pragma unroll
        for (int cf = 0; cf < 16; ++cf) {
            int col = (cf << 4) + lr;
            int a = lds_off(row, col << 1);
            float v = acc[cf][reg] + bf2f(*(unsigned short*)(hb + a)) + b1[col];
            *(unsigned short*)(hb + a) = f2bf(fmaxf(v, 0.f));
        }
    }
    __syncthreads();

    // --- phase 2: h2 = relu(h @ W2 + b2); wave owns cols [wv*64, wv*64+64)
    f32x4 acc2[4][4];
    #pragma unroll
    for (int i = 0; i < 4; ++i)
        #pragma unroll
        for (int j = 0; j < 4; ++j) acc2[i][j] = zero;

    #pragma unroll 2
    for (int kb = 0; kb < 8; ++kb) {
        short8 a[4];
        #pragma unroll
        for (int mr = 0; mr < 4; ++mr)
            a[mr] = *(const short8*)(hb +
                lds_off(mr * 16 + lr, ((kb << 5) + (lg << 3)) << 1));
        #pragma unroll
        for (int mr = 0; mr < 4; ++mr)
            #pragma unroll
            for (int nf = 0; nf < 4; ++nf)
                acc2[mr][nf] = __builtin_amdgcn_mfma_f32_16x16x32_bf16(
                    a[mr],
                    ((const short8*)w2p)[(size_t)(kb * 16 + (wv << 2) + nf) * 64 + l],
                    acc2[mr][nf], 0, 0, 0);
    }
    __syncthreads();  // all phase-2 h reads done before overwrite

    #pragma unroll
    for (int mr = 0; mr < 4; ++mr)
        #pragma unroll
        for (int reg = 0; reg < 4; ++reg) {
            int row = mr * 16 + (lg << 2) + reg;
            #pragma unroll
            for (int nf = 0; nf < 4; ++nf) {
                int col = (wv << 6) + (nf << 4) + lr;
                float v = fmaxf(acc2[mr][nf][reg] + b2[col], 0.f);
                *(unsigned short*)(hb + lds_off(row, col << 1)) = f2bf(v);
            }
        }
    __syncthreads();

    // --- phase 3: out = h2 @ W3 + b3; wave owns cols [wv*32, wv*32+32)
    f32x4 acc3[4][2];
    #pragma unroll
    for (int i = 0; i < 4; ++i) { acc3[i][0] = zero; acc3[i][1] = zero; }

    #pragma unroll 2
    for (int kb = 0; kb < 8; ++kb) {
        short8 a[4];
        #pragma unroll
        for (int mr = 0; mr < 4; ++mr)
            a[mr] = *(const short8*)(hb +
                lds_off(mr * 16 + lr, ((kb << 5) + (lg << 3)) << 1));
        #pragma unroll
        for (int mr = 0; mr < 4; ++mr)
            #pragma unroll
            for (int nf = 0; nf < 2; ++nf)
                acc3[mr][nf] = __builtin_amdgcn_mfma_f32_16x16x32_bf16(
                    a[mr],
                    ((const short8*)w3p)[(size_t)(kb * 8 + (wv << 1) + nf) * 64 + l],
                    acc3[mr][nf], 0, 0, 0);
    }

    float* op = out + ((size_t)d * E_NUM + e0) * 128;
    #pragma unroll
    for (int mr = 0; mr < 4; ++mr)
        #pragma unroll
        for (int reg = 0; reg < 4; ++reg) {
            int row = mr * 16 + (lg << 2) + reg;
            #pragma unroll
            for (int nf = 0; nf < 2; ++nf) {
                int col = (wv << 5) + (nf << 4) + lr;
                op[(size_t)row * 128 + col] = acc3[mr][nf][reg] + b3[col];
            }
        }
}

extern "C" void kernel_launch(void* const* d_in, const int* in_sizes, int n_in,
                              void* d_out, int out_size, void* d_ws, size_t ws_size,
                              hipStream_t stream) {
    const int* ei     = (const int*)d_in[0];
    const float* attr = (const float*)d_in[1];
    const float* W1   = (const float*)d_in[2];
    const float* b1   = (const float*)d_in[3];
    const float* W2   = (const float*)d_in[4];
    const float* b2   = (const float*)d_in[5];
    const float* W3   = (const float*)d_in[6];
    const float* b3   = (const float*)d_in[7];
    float* out = (float*)d_out;
    const float* W1rel = W1 + (size_t)N_ENT * 256;

    unsigned short* w1rp = (unsigned short*)d_ws;   //  64x256 bf16 =  32 KB
    unsigned short* w2p  = w1rp + 64 * 256;         // 256x256 bf16 = 128 KB
    unsigned short* w3p  = w2p + 256 * 256;         // 256x128 bf16 =  64 KB

    pack_b_kernel<<<(64 * 256) / 256, 256, 0, stream>>>(W1rel, w1rp, 64, 256);
    pack_b_kernel<<<(256 * 256) / 256, 256, 0, stream>>>(W2, w2p, 256, 256);
    pack_b_kernel<<<(256 * 128) / 256, 256, 0, stream>>>(W3, w3p, 256, 128);

    // 2 directions x 6250 tiles of 64 edges (exact, no tail)
    fused2<<<12500, 256, 0, stream>>>(ei, attr, W1, b1, b2, b3,
                                      w1rp, w2p, w3p, out);
}